// Round 17
// baseline (49.665 us; speedup 1.0000x reference)
//
#include <hip/hip_runtime.h>
#include <stdint.h>

// B=8, Q=2048, D=256, H=8, L=3, P=4, HD=32
// vproj rows: level-major, T={2048,1024,512}, LOFF={0,16384,24576}, total 28672

typedef __attribute__((ext_vector_type(8))) short bf16x8;
typedef __attribute__((ext_vector_type(8))) unsigned short u16x8;
typedef __attribute__((ext_vector_type(4))) float f32x4;

__device__ __forceinline__ unsigned short f2bf(float f) {
    union { float f; uint32_t u; } v; v.f = f;
    return (unsigned short)((v.u + 0x7FFFu + ((v.u >> 16) & 1u)) >> 16);  // RNE
}
__device__ __forceinline__ float bf2f(unsigned short u) {
    union { uint32_t u; float f; } v; v.u = ((uint32_t)u) << 16;
    return v.f;
}

// ---------------------------------------------------------------------------
// K12: merged GEMMs, small tiles (960 blocks), T14 register-prefetch pipeline:
// issue tile k+1's global loads BEFORE the MFMA of tile k; convert+write LDS
// at the top of iteration k+1. HBM latency hides under MFMA + barriers.
//  blocks 0..447  : vproj tile 64x128 (batch = bid&7).
//  blocks 448..959: logits tile 32x192 (batch = lid&7) + softmax + sidx.
// No min-waves launch_bounds (round 9 spill). No NT hints (round 14).
// ---------------------------------------------------------------------------
__global__ __launch_bounds__(256) void fused_k12_kernel(
    const float* __restrict__ v0, const float* __restrict__ v1,
    const float* __restrict__ v2,
    const float* __restrict__ Wv, const float* __restrict__ bv,
    unsigned short* __restrict__ vproj,
    const float* __restrict__ query,
    const float* __restrict__ Woff, const float* __restrict__ Waw,
    const float* __restrict__ boff, const float* __restrict__ baw,
    const float* __restrict__ refp, float* __restrict__ rows)
{
    __shared__ __align__(16) char SMEM[25344];   // union: staging | epilogue
    const int t = threadIdx.x;
    const int bid = blockIdx.x;
    const int w = t >> 6, lane = t & 63;
    const int fr = lane & 15, sl = lane >> 4;

    if (bid < 448) {
        // ============ vproj path: 64x128 tile (batch = bid&7) =============
        auto Asub = reinterpret_cast<unsigned short(*)[64][8]>(SMEM);           // 4 KB
        auto Bsub = reinterpret_cast<unsigned short(*)[128][8]>(SMEM + 4096);   // 8 KB

        const int b = bid & 7;
        const int j = bid >> 3;                  // 0..55
        int l, tile;
        if (j < 32)      { l = 0; tile = j; }
        else if (j < 48) { l = 1; tile = j - 32; }
        else             { l = 2; tile = j - 48; }
        const int T = 2048 >> l;
        const int loff = (l == 0) ? 0 : ((l == 1) ? 16384 : 24576);
        const int row0 = loff + b * T + tile * 64;
        const int arow = b * T + tile * 64;
        const float* Ap = (l == 0) ? v0 : ((l == 1) ? v1 : v2);

        const int ar = t >> 2, as = t & 3;       // A staging: row 0..63, slot
        const int wr = w >> 1, wc = w & 1;       // wave: 32 rows x 64 cols

        f32x4 acc[2][4];
#pragma unroll
        for (int m = 0; m < 2; ++m)
#pragma unroll
            for (int n = 0; n < 4; ++n) acc[m][n] = (f32x4){0.f, 0.f, 0.f, 0.f};

        // prefetch tile 0 into registers
        float4 pa0, pa1;
        float pb[2][8];
        {
            const float* src = &Ap[(size_t)(arow + ar) * 256 + as * 8];
            pa0 = *reinterpret_cast<const float4*>(src);
            pa1 = *reinterpret_cast<const float4*>(src + 4);
#pragma unroll
            for (int i = 0; i < 2; ++i) {
                const int ch = t + i * 256;
                const int slot = ch >> 7, col = ch & 127;
#pragma unroll
                for (int jj = 0; jj < 8; ++jj)
                    pb[i][jj] = Wv[(size_t)(slot * 8 + jj) * 256 + col];
            }
        }

        for (int k0t = 0; k0t < 8; ++k0t) {
            {   // write staged tile (regs -> bf16 -> LDS)
                u16x8 pk;
                pk[0]=f2bf(pa0.x); pk[1]=f2bf(pa0.y); pk[2]=f2bf(pa0.z); pk[3]=f2bf(pa0.w);
                pk[4]=f2bf(pa1.x); pk[5]=f2bf(pa1.y); pk[6]=f2bf(pa1.z); pk[7]=f2bf(pa1.w);
                *reinterpret_cast<u16x8*>(&Asub[as][ar][0]) = pk;
#pragma unroll
                for (int i = 0; i < 2; ++i) {
                    const int ch = t + i * 256;
                    const int slot = ch >> 7, col = ch & 127;
                    u16x8 pk2;
#pragma unroll
                    for (int jj = 0; jj < 8; ++jj) pk2[jj] = f2bf(pb[i][jj]);
                    *reinterpret_cast<u16x8*>(&Bsub[slot][col][0]) = pk2;
                }
            }
            __syncthreads();

            if (k0t < 7) {   // issue tile k+1 loads (hide under MFMA below)
                const int k0n = (k0t + 1) * 32;
                const float* src = &Ap[(size_t)(arow + ar) * 256 + k0n + as * 8];
                pa0 = *reinterpret_cast<const float4*>(src);
                pa1 = *reinterpret_cast<const float4*>(src + 4);
#pragma unroll
                for (int i = 0; i < 2; ++i) {
                    const int ch = t + i * 256;
                    const int slot = ch >> 7, col = ch & 127;
#pragma unroll
                    for (int jj = 0; jj < 8; ++jj)
                        pb[i][jj] = Wv[(size_t)(k0n + slot * 8 + jj) * 256 + col];
                }
            }

            bf16x8 bfrag[4];
#pragma unroll
            for (int n = 0; n < 4; ++n)
                bfrag[n] = *reinterpret_cast<bf16x8*>(&Bsub[sl][wc * 64 + n * 16 + fr][0]);
#pragma unroll
            for (int m = 0; m < 2; ++m) {
                bf16x8 afrag = *reinterpret_cast<bf16x8*>(&Asub[sl][wr * 32 + m * 16 + fr][0]);
#pragma unroll
                for (int n = 0; n < 4; ++n)
                    acc[m][n] = __builtin_amdgcn_mfma_f32_16x16x32_bf16(afrag, bfrag[n], acc[m][n], 0, 0, 0);
            }
            __syncthreads();
        }

        float bs[4];
#pragma unroll
        for (int n = 0; n < 4; ++n) bs[n] = bv[wc * 64 + n * 16 + fr];

        auto Epi2 = reinterpret_cast<float(*)[132]>(SMEM);   // [32][132], aliases staging
#pragma unroll
        for (int m = 0; m < 2; ++m) {
#pragma unroll
            for (int n = 0; n < 4; ++n)
#pragma unroll
                for (int jj = 0; jj < 4; ++jj)
                    Epi2[wr * 16 + sl * 4 + jj][wc * 64 + n * 16 + fr] = acc[m][n][jj] + bs[n];
            __syncthreads();
#pragma unroll
            for (int i = 0; i < 2; ++i) {            // 32x128 bf16 = 512 chunks
                const int idx = t + i * 256;
                const int rb = idx >> 4, c8 = idx & 15;
                const int grow = row0 + m * 16 + (rb >> 4) * 32 + (rb & 15);
                u16x8 pk;
#pragma unroll
                for (int e = 0; e < 8; ++e) pk[e] = f2bf(Epi2[rb][c8 * 8 + e]);
                *reinterpret_cast<u16x8*>(&vproj[(size_t)grow * 128 + c8 * 8]) = pk;
            }
            __syncthreads();
        }
    } else {
        // ============ logits path: 32x192 tile (batch = lid&7) ============
        auto Asub = reinterpret_cast<unsigned short(*)[32][8]>(SMEM);           // 2 KB
        auto Bsub = reinterpret_cast<unsigned short(*)[192][8]>(SMEM + 2048);   // 12 KB

        const int lid = bid - 448;               // 448 % 8 == 0
        const int qrow0 = (lid & 7) * 2048 + (lid >> 3) * 32;
        const int wr = w >> 1, wc = w & 1;       // wave: 16 rows x 96 cols

        f32x4 acc[6];
#pragma unroll
        for (int n = 0; n < 6; ++n) acc[n] = (f32x4){0.f, 0.f, 0.f, 0.f};

        const int ar = t >> 2, as = t & 3;       // A staging (t<128): row, slot

        // prefetch tile 0 into registers
        float4 pa0, pa1;
        float pb[3][8];
        {
            if (t < 128) {
                const float* src = &query[(size_t)(qrow0 + ar) * 256 + as * 8];
                pa0 = *reinterpret_cast<const float4*>(src);
                pa1 = *reinterpret_cast<const float4*>(src + 4);
            }
#pragma unroll
            for (int i = 0; i < 3; ++i) {
                const int c = t + i * 256;
                const int slot = c / 192, col = c % 192;
#pragma unroll
                for (int jj = 0; jj < 8; ++jj) {
                    const int kk = slot * 8 + jj;
                    pb[i][jj] = (col < 96) ? Woff[kk * 96 + col]
                                           : Waw[kk * 96 + (col - 96)];
                }
            }
        }

        for (int k0t = 0; k0t < 8; ++k0t) {
            {   // write staged tile (regs -> bf16 -> LDS)
                if (t < 128) {
                    u16x8 pk;
                    pk[0]=f2bf(pa0.x); pk[1]=f2bf(pa0.y); pk[2]=f2bf(pa0.z); pk[3]=f2bf(pa0.w);
                    pk[4]=f2bf(pa1.x); pk[5]=f2bf(pa1.y); pk[6]=f2bf(pa1.z); pk[7]=f2bf(pa1.w);
                    *reinterpret_cast<u16x8*>(&Asub[as][ar][0]) = pk;
                }
#pragma unroll
                for (int i = 0; i < 3; ++i) {
                    const int c = t + i * 256;
                    const int slot = c / 192, col = c % 192;
                    u16x8 pk2;
#pragma unroll
                    for (int jj = 0; jj < 8; ++jj) pk2[jj] = f2bf(pb[i][jj]);
                    *reinterpret_cast<u16x8*>(&Bsub[slot][col][0]) = pk2;
                }
            }
            __syncthreads();

            if (k0t < 7) {   // issue tile k+1 loads
                const int k0n = (k0t + 1) * 32;
                if (t < 128) {
                    const float* src = &query[(size_t)(qrow0 + ar) * 256 + k0n + as * 8];
                    pa0 = *reinterpret_cast<const float4*>(src);
                    pa1 = *reinterpret_cast<const float4*>(src + 4);
                }
#pragma unroll
                for (int i = 0; i < 3; ++i) {
                    const int c = t + i * 256;
                    const int slot = c / 192, col = c % 192;
#pragma unroll
                    for (int jj = 0; jj < 8; ++jj) {
                        const int kk = k0n + slot * 8 + jj;
                        pb[i][jj] = (col < 96) ? Woff[kk * 96 + col]
                                               : Waw[kk * 96 + (col - 96)];
                    }
                }
            }

            bf16x8 afrag = *reinterpret_cast<bf16x8*>(&Asub[sl][wr * 16 + fr][0]);
#pragma unroll
            for (int n = 0; n < 6; ++n) {
                bf16x8 bfrag = *reinterpret_cast<bf16x8*>(&Bsub[sl][wc * 96 + n * 16 + fr][0]);
                acc[n] = __builtin_amdgcn_mfma_f32_16x16x32_bf16(afrag, bfrag, acc[n], 0, 0, 0);
            }
            __syncthreads();
        }

        // Epilogue: all 32 rows at once through the union buffer.
        auto Epi = reinterpret_cast<float(*)[196]>(SMEM);    // [32][196]
#pragma unroll
        for (int n = 0; n < 6; ++n) {
            const int col = wc * 96 + n * 16 + fr;
            const float bsn = (col < 96) ? boff[col] : baw[col - 96];
#pragma unroll
            for (int jj = 0; jj < 4; ++jj)
                Epi[wr * 16 + sl * 4 + jj][col] = acc[n][jj] + bsn;
        }
        __syncthreads();

        // softmax + sidx: 32 q x 8 h = 256 pairs, 1 per thread
        {
            const int q = t >> 3, h = t & 7;
            const float ref = refp[qrow0 + q];
            float* lg = &Epi[q][96 + h * 12];
            float mx = -1e30f;
#pragma unroll
            for (int jj = 0; jj < 12; ++jj) mx = fmaxf(mx, lg[jj]);
            float e[12]; float s = 0.f;
#pragma unroll
            for (int jj = 0; jj < 12; ++jj) { e[jj] = expf(lg[jj] - mx); s += e[jj]; }
            const float inv = 1.f / s;
#pragma unroll
            for (int jj = 0; jj < 12; ++jj) lg[jj] = e[jj] * inv;
            float* off = &Epi[q][h * 12];
#pragma unroll
            for (int jj = 0; jj < 12; ++jj) {
                const int l = jj >> 2;
                const int T = 2048 >> l;
                float pos = ref + off[jj] / (float)T;
                pos = fminf(fmaxf(pos, 0.f), 1.f);
                off[jj] = pos * (float)(T - 1);
            }
        }
        __syncthreads();

        // Coalesced writeout: 32 x 192 f32 = 1536 float4, 6 per thread.
#pragma unroll
        for (int i = 0; i < 6; ++i) {
            const int idx = t + i * 256;
            const int q = idx / 48, c4 = idx % 48;
            const float4 o = *reinterpret_cast<const float4*>(&Epi[q][c4 * 4]);
            *reinterpret_cast<float4*>(&rows[(size_t)(qrow0 + q) * 192 + c4 * 4]) = o;
        }
    }
}

// ---------------------------------------------------------------------------
// K3: gather + lerp + weighted sum, 4x vectorized.
// One wave per query (8 heads x 8 channel-quads), 4 queries per block.
// ushort4 (8B) gathers; grid 4096 with bid&7 = batch -> XCD L2 affinity.
// ---------------------------------------------------------------------------
__global__ __launch_bounds__(256) void sample_kernel(
    const float* __restrict__ rows,            // [16384,192]  sidx | aw
    const unsigned short* __restrict__ vproj,  // [28672,128]  bf16, level-major
    unsigned short* __restrict__ out_mid)      // [16384,256]  bf16
{
    const int bid = blockIdx.x;                // 0..4095
    const int b = bid & 7;
    const int q0 = (b << 11) + ((bid >> 3) << 2);   // 4 queries/block
    const int t = threadIdx.x;
    const int w = t >> 6, lane = t & 63;
    const int h = lane >> 3, c4 = lane & 7;    // channel = c4*4 .. +3

    __shared__ float srow[4][192];
    {
        const float* src = rows + (size_t)q0 * 192;
#pragma unroll
        for (int i = 0; i < 3; ++i) {
            const int idx = t + i * 256;       // 0..767, coalesced
            srow[idx / 192][idx % 192] = src[idx];
        }
    }
    __syncthreads();

    float acc0 = 0.f, acc1 = 0.f, acc2 = 0.f, acc3 = 0.f;
#pragma unroll
    for (int l = 0; l < 3; ++l) {
        const int T = 2048 >> l;
        const int loff = (l == 0) ? 0 : ((l == 1) ? 16384 : 24576);
#pragma unroll
        for (int p = 0; p < 4; ++p) {
            const int j = h * 12 + l * 4 + p;
            const float wgt  = srow[w][96 + j];
            const float sidx = srow[w][j];
            int ifl = (int)sidx;
            ifl = min(max(ifl, 0), T - 2);
            const float wce = sidx - (float)ifl;
            const size_t base = ((size_t)(loff + b * T + ifl)) * 128 + p * 32 + c4 * 4;
            const ushort4 vf = *reinterpret_cast<const ushort4*>(&vproj[base]);
            const ushort4 vc = *reinterpret_cast<const ushort4*>(&vproj[base + 128]);
            const float f0 = bf2f(vf.x), f1 = bf2f(vf.y), f2 = bf2f(vf.z), f3 = bf2f(vf.w);
            const float g0 = bf2f(vc.x), g1 = bf2f(vc.y), g2 = bf2f(vc.z), g3 = bf2f(vc.w);
            acc0 += wgt * (f0 + wce * (g0 - f0));
            acc1 += wgt * (f1 + wce * (g1 - f1));
            acc2 += wgt * (f2 + wce * (g2 - f2));
            acc3 += wgt * (f3 + wce * (g3 - f3));
        }
    }
    ushort4 o;
    o.x = f2bf(acc0); o.y = f2bf(acc1); o.z = f2bf(acc2); o.w = f2bf(acc3);
    *reinterpret_cast<ushort4*>(&out_mid[(size_t)(q0 + w) * 256 + h * 32 + c4 * 4]) = o;
}

// ---------------------------------------------------------------------------
// K4: output projection, 64x128 tiles -> 512 blocks (2/CU) for latency hiding.
// b = bid&7, row-tile = (bid>>3)&31, col-tile = bid>>8.
// ---------------------------------------------------------------------------
__global__ __launch_bounds__(256) void outproj_kernel(
    const unsigned short* __restrict__ omid,   // [16384,256] bf16
    const float* __restrict__ Wo,              // [256][256] f32
    const float* __restrict__ bo,
    float* __restrict__ out)
{
    __shared__ __align__(16) char SMEM[16896];   // union: staging 12K | epi 16.9K
    auto Asub = reinterpret_cast<unsigned short(*)[64][8]>(SMEM);           // 4 KB
    auto Bsub = reinterpret_cast<unsigned short(*)[128][8]>(SMEM + 4096);   // 8 KB

    const int t = threadIdx.x;
    const int bid = blockIdx.x;
    const int b = bid & 7;
    const int row0 = b * 2048 + ((bid >> 3) & 31) * 64;
    const int col0 = (bid >> 8) * 128;

    const int ar = t >> 2, as = t & 3;           // A staging: row 0..63, slot
    const int w = t >> 6, lane = t & 63;
    const int wr = w >> 1, wc = w & 1;           // wave: 32 rows x 64 cols
    const int fr = lane & 15, sl = lane >> 4;

    f32x4 acc[2][4];
#pragma unroll
    for (int m = 0; m < 2; ++m)
#pragma unroll
        for (int n = 0; n < 4; ++n) acc[m][n] = (f32x4){0.f, 0.f, 0.f, 0.f};

    for (int k0t = 0; k0t < 8; ++k0t) {
        const int k0 = k0t * 32;
        {   // stage A: 16B copies (bf16 src), 1 chunk/thread
            *reinterpret_cast<u16x8*>(&Asub[as][ar][0]) =
                *reinterpret_cast<const u16x8*>(&omid[(size_t)(row0 + ar) * 256 + k0 + as * 8]);
        }
        {   // stage B from raw Wo, 2 chunks/thread
#pragma unroll
            for (int i = 0; i < 2; ++i) {
                const int ch = t + i * 256;
                const int slot = ch >> 7, col = col0 + (ch & 127);
                u16x8 pk;
#pragma unroll
                for (int jj = 0; jj < 8; ++jj)
                    pk[jj] = f2bf(Wo[(size_t)(k0 + slot * 8 + jj) * 256 + col]);
                *reinterpret_cast<u16x8*>(&Bsub[slot][ch & 127][0]) = pk;
            }
        }
        __syncthreads();

        bf16x8 bfrag[4];
#pragma unroll
        for (int n = 0; n < 4; ++n)
            bfrag[n] = *reinterpret_cast<bf16x8*>(&Bsub[sl][wc * 64 + n * 16 + fr][0]);
#pragma unroll
        for (int m = 0; m < 2; ++m) {
            bf16x8 afrag = *reinterpret_cast<bf16x8*>(&Asub[sl][wr * 32 + m * 16 + fr][0]);
#pragma unroll
            for (int n = 0; n < 4; ++n)
                acc[m][n] = __builtin_amdgcn_mfma_f32_16x16x32_bf16(afrag, bfrag[n], acc[m][n], 0, 0, 0);
        }
        __syncthreads();
    }

    float bs[4];
#pragma unroll
    for (int n = 0; n < 4; ++n) bs[n] = bo[col0 + wc * 64 + n * 16 + fr];

    auto Epi2 = reinterpret_cast<float(*)[132]>(SMEM);   // [32][132], aliases staging
#pragma unroll
    for (int m = 0; m < 2; ++m) {
#pragma unroll
        for (int n = 0; n < 4; ++n)
#pragma unroll
            for (int j = 0; j < 4; ++j)
                Epi2[wr * 16 + sl * 4 + j][wc * 64 + n * 16 + fr] = acc[m][n][j] + bs[n];
        __syncthreads();
#pragma unroll
        for (int i = 0; i < 4; ++i) {            // 32x128 f32 = 1024 float4
            const int idx = t + i * 256;
            const int rb = idx >> 5, c4 = idx & 31;
            const int grow = row0 + m * 16 + (rb >> 4) * 32 + (rb & 15);
            const float4 o = *reinterpret_cast<const float4*>(&Epi2[rb][c4 * 4]);
            *reinterpret_cast<float4*>(&out[(size_t)grow * 256 + col0 + c4 * 4]) = o;
        }
        __syncthreads();
    }
}

extern "C" void kernel_launch(void* const* d_in, const int* in_sizes, int n_in,
                              void* d_out, int out_size, void* d_ws, size_t ws_size,
                              hipStream_t stream) {
    (void)in_sizes; (void)n_in; (void)out_size; (void)ws_size;
    const float* query = (const float*)d_in[0];
    const float* refp  = (const float*)d_in[1];
    const float* v0    = (const float*)d_in[2];
    const float* v1    = (const float*)d_in[3];
    const float* v2    = (const float*)d_in[4];
    const float* Woff  = (const float*)d_in[5];
    const float* boff  = (const float*)d_in[6];
    const float* Waw   = (const float*)d_in[7];
    const float* baw   = (const float*)d_in[8];
    const float* Wv    = (const float*)d_in[9];
    const float* bv    = (const float*)d_in[10];
    const float* Wo    = (const float*)d_in[11];
    const float* bo    = (const float*)d_in[12];
    float* out = (float*)d_out;

    char* ws = (char*)d_ws;
    unsigned short* vproj = (unsigned short*)(ws);             // 7,340,032 B
    float*          rows  = (float*)(ws + 7340032);            // 12,582,912 B
    unsigned short* omid  = (unsigned short*)(ws + 19922944);  // 8,388,608 B

    // K12: merged vproj + logits (register-prefetch pipelined K-loop)
    fused_k12_kernel<<<960, 256, 0, stream>>>(v0, v1, v2, Wv, bv, vproj,
                                              query, Woff, Waw, boff, baw,
                                              refp, rows);

    // K3: gather + lerp + weighted sum (vectorized, XCD-aligned)
    sample_kernel<<<4096, 256, 0, stream>>>(rows, vproj, omid);

    // K4: output projection (64x128 tiles, 512 blocks)
    outproj_kernel<<<512, 256, 0, stream>>>(omid, Wo, bo, out);
}

// Round 19
// 47.550 us; speedup vs baseline: 1.0445x; 1.0445x over previous
//
#include <hip/hip_runtime.h>
#include <stdint.h>

// B=8, Q=2048, D=256, H=8, L=3, P=4, HD=32
// vproj rows: level-major, T={2048,1024,512}, LOFF={0,16384,24576}, total 28672

typedef __attribute__((ext_vector_type(8))) short bf16x8;
typedef __attribute__((ext_vector_type(8))) unsigned short u16x8;
typedef __attribute__((ext_vector_type(4))) float f32x4;

__device__ __forceinline__ unsigned short f2bf(float f) {
    union { float f; uint32_t u; } v; v.f = f;
    return (unsigned short)((v.u + 0x7FFFu + ((v.u >> 16) & 1u)) >> 16);  // RNE
}
__device__ __forceinline__ float bf2f(unsigned short u) {
    union { uint32_t u; float f; } v; v.u = ((uint32_t)u) << 16;
    return v.f;
}

// ---------------------------------------------------------------------------
// K12: merged GEMMs, small tiles for grid-level latency hiding (960 blocks).
//  blocks 0..447  : vproj tile 64x128 (batch = bid&7, 56 tiles/batch).
//  blocks 448..959: logits tile 32x192 (batch = lid&7) + softmax + sidx.
// Proven config (R13/R16: 47.6/47.8 µs). Rejected variants, all measured:
//  - launch_bounds(256,6): VGPR cap 40 -> accumulator spill, +32 µs (R9)
//  - NT loads/stores: consumers lose L2 hits, +8 µs (R14)
//  - register-prefetch pipeline: +2 µs (R17, compiler already overlaps)
// ---------------------------------------------------------------------------
__global__ __launch_bounds__(256) void fused_k12_kernel(
    const float* __restrict__ v0, const float* __restrict__ v1,
    const float* __restrict__ v2,
    const float* __restrict__ Wv, const float* __restrict__ bv,
    unsigned short* __restrict__ vproj,
    const float* __restrict__ query,
    const float* __restrict__ Woff, const float* __restrict__ Waw,
    const float* __restrict__ boff, const float* __restrict__ baw,
    const float* __restrict__ refp, float* __restrict__ rows)
{
    __shared__ __align__(16) char SMEM[25344];   // union: staging | epilogue
    const int t = threadIdx.x;
    const int bid = blockIdx.x;
    const int w = t >> 6, lane = t & 63;
    const int fr = lane & 15, sl = lane >> 4;

    if (bid < 448) {
        // ============ vproj path: 64x128 tile (batch = bid&7) =============
        auto Asub = reinterpret_cast<unsigned short(*)[64][8]>(SMEM);           // 4 KB
        auto Bsub = reinterpret_cast<unsigned short(*)[128][8]>(SMEM + 4096);   // 8 KB

        const int b = bid & 7;
        const int j = bid >> 3;                  // 0..55
        int l, tile;
        if (j < 32)      { l = 0; tile = j; }
        else if (j < 48) { l = 1; tile = j - 32; }
        else             { l = 2; tile = j - 48; }
        const int T = 2048 >> l;
        const int loff = (l == 0) ? 0 : ((l == 1) ? 16384 : 24576);
        const int row0 = loff + b * T + tile * 64;
        const int arow = b * T + tile * 64;
        const float* Ap = (l == 0) ? v0 : ((l == 1) ? v1 : v2);

        const int ar = t >> 2, as = t & 3;       // A staging: row 0..63, slot
        const int wr = w >> 1, wc = w & 1;       // wave: 32 rows x 64 cols

        f32x4 acc[2][4];
#pragma unroll
        for (int m = 0; m < 2; ++m)
#pragma unroll
            for (int n = 0; n < 4; ++n) acc[m][n] = (f32x4){0.f, 0.f, 0.f, 0.f};

        for (int k0t = 0; k0t < 8; ++k0t) {
            const int k0 = k0t * 32;
            {   // stage A: 64 rows x 32 k (f32 -> bf16), 1 chunk/thread
                const float* src = &Ap[(size_t)(arow + ar) * 256 + k0 + as * 8];
                const float4 f0 = *reinterpret_cast<const float4*>(src);
                const float4 f1 = *reinterpret_cast<const float4*>(src + 4);
                u16x8 pk;
                pk[0]=f2bf(f0.x); pk[1]=f2bf(f0.y); pk[2]=f2bf(f0.z); pk[3]=f2bf(f0.w);
                pk[4]=f2bf(f1.x); pk[5]=f2bf(f1.y); pk[6]=f2bf(f1.z); pk[7]=f2bf(f1.w);
                *reinterpret_cast<u16x8*>(&Asub[as][ar][0]) = pk;
            }
            {   // stage B from raw Wv (cols 0..127), 2 chunks/thread
#pragma unroll
                for (int i = 0; i < 2; ++i) {
                    const int ch = t + i * 256;
                    const int slot = ch >> 7, col = ch & 127;
                    u16x8 pk;
#pragma unroll
                    for (int jj = 0; jj < 8; ++jj)
                        pk[jj] = f2bf(Wv[(size_t)(k0 + slot * 8 + jj) * 256 + col]);
                    *reinterpret_cast<u16x8*>(&Bsub[slot][col][0]) = pk;
                }
            }
            __syncthreads();

            bf16x8 bfrag[4];
#pragma unroll
            for (int n = 0; n < 4; ++n)
                bfrag[n] = *reinterpret_cast<bf16x8*>(&Bsub[sl][wc * 64 + n * 16 + fr][0]);
#pragma unroll
            for (int m = 0; m < 2; ++m) {
                bf16x8 afrag = *reinterpret_cast<bf16x8*>(&Asub[sl][wr * 32 + m * 16 + fr][0]);
#pragma unroll
                for (int n = 0; n < 4; ++n)
                    acc[m][n] = __builtin_amdgcn_mfma_f32_16x16x32_bf16(afrag, bfrag[n], acc[m][n], 0, 0, 0);
            }
            __syncthreads();
        }

        float bs[4];
#pragma unroll
        for (int n = 0; n < 4; ++n) bs[n] = bv[wc * 64 + n * 16 + fr];

        auto Epi2 = reinterpret_cast<float(*)[132]>(SMEM);   // [32][132], aliases staging
#pragma unroll
        for (int m = 0; m < 2; ++m) {
#pragma unroll
            for (int n = 0; n < 4; ++n)
#pragma unroll
                for (int jj = 0; jj < 4; ++jj)
                    Epi2[wr * 16 + sl * 4 + jj][wc * 64 + n * 16 + fr] = acc[m][n][jj] + bs[n];
            __syncthreads();
#pragma unroll
            for (int i = 0; i < 2; ++i) {            // 32x128 bf16 = 512 chunks
                const int idx = t + i * 256;
                const int rb = idx >> 4, c8 = idx & 15;
                const int grow = row0 + m * 16 + (rb >> 4) * 32 + (rb & 15);
                u16x8 pk;
#pragma unroll
                for (int e = 0; e < 8; ++e) pk[e] = f2bf(Epi2[rb][c8 * 8 + e]);
                *reinterpret_cast<u16x8*>(&vproj[(size_t)grow * 128 + c8 * 8]) = pk;
            }
            __syncthreads();
        }
    } else {
        // ============ logits path: 32x192 tile (batch = lid&7) ============
        auto Asub = reinterpret_cast<unsigned short(*)[32][8]>(SMEM);           // 2 KB
        auto Bsub = reinterpret_cast<unsigned short(*)[192][8]>(SMEM + 2048);   // 12 KB

        const int lid = bid - 448;               // 448 % 8 == 0
        const int qrow0 = (lid & 7) * 2048 + (lid >> 3) * 32;
        const int wr = w >> 1, wc = w & 1;       // wave: 16 rows x 96 cols

        f32x4 acc[6];
#pragma unroll
        for (int n = 0; n < 6; ++n) acc[n] = (f32x4){0.f, 0.f, 0.f, 0.f};

        const int ar = t >> 2, as = t & 3;       // A staging (t<128): row, slot

        for (int k0t = 0; k0t < 8; ++k0t) {
            const int k0 = k0t * 32;
            if (t < 128) {   // stage A: 32 rows x 32 k
                const float* src = &query[(size_t)(qrow0 + ar) * 256 + k0 + as * 8];
                const float4 f0 = *reinterpret_cast<const float4*>(src);
                const float4 f1 = *reinterpret_cast<const float4*>(src + 4);
                u16x8 pk;
                pk[0]=f2bf(f0.x); pk[1]=f2bf(f0.y); pk[2]=f2bf(f0.z); pk[3]=f2bf(f0.w);
                pk[4]=f2bf(f1.x); pk[5]=f2bf(f1.y); pk[6]=f2bf(f1.z); pk[7]=f2bf(f1.w);
                *reinterpret_cast<u16x8*>(&Asub[as][ar][0]) = pk;
            }
            {   // stage B from raw [Woff|Waw], 3 chunks/thread
#pragma unroll
                for (int i = 0; i < 3; ++i) {
                    const int c = t + i * 256;      // 0..767
                    const int slot = c / 192, col = c % 192;
                    u16x8 pk;
#pragma unroll
                    for (int jj = 0; jj < 8; ++jj) {
                        const int kk = k0 + slot * 8 + jj;
                        const float v = (col < 96) ? Woff[kk * 96 + col]
                                                   : Waw[kk * 96 + (col - 96)];
                        pk[jj] = f2bf(v);
                    }
                    *reinterpret_cast<u16x8*>(&Bsub[slot][col][0]) = pk;
                }
            }
            __syncthreads();

            bf16x8 afrag = *reinterpret_cast<bf16x8*>(&Asub[sl][wr * 16 + fr][0]);
#pragma unroll
            for (int n = 0; n < 6; ++n) {
                bf16x8 bfrag = *reinterpret_cast<bf16x8*>(&Bsub[sl][wc * 96 + n * 16 + fr][0]);
                acc[n] = __builtin_amdgcn_mfma_f32_16x16x32_bf16(afrag, bfrag, acc[n], 0, 0, 0);
            }
            __syncthreads();
        }

        // Epilogue: all 32 rows at once through the union buffer.
        auto Epi = reinterpret_cast<float(*)[196]>(SMEM);    // [32][196]
#pragma unroll
        for (int n = 0; n < 6; ++n) {
            const int col = wc * 96 + n * 16 + fr;
            const float bsn = (col < 96) ? boff[col] : baw[col - 96];
#pragma unroll
            for (int jj = 0; jj < 4; ++jj)
                Epi[wr * 16 + sl * 4 + jj][col] = acc[n][jj] + bsn;
        }
        __syncthreads();

        // softmax + sidx: 32 q x 8 h = 256 pairs, 1 per thread
        {
            const int q = t >> 3, h = t & 7;
            const float ref = refp[qrow0 + q];
            float* lg = &Epi[q][96 + h * 12];
            float mx = -1e30f;
#pragma unroll
            for (int jj = 0; jj < 12; ++jj) mx = fmaxf(mx, lg[jj]);
            float e[12]; float s = 0.f;
#pragma unroll
            for (int jj = 0; jj < 12; ++jj) { e[jj] = expf(lg[jj] - mx); s += e[jj]; }
            const float inv = 1.f / s;
#pragma unroll
            for (int jj = 0; jj < 12; ++jj) lg[jj] = e[jj] * inv;
            float* off = &Epi[q][h * 12];
#pragma unroll
            for (int jj = 0; jj < 12; ++jj) {
                const int l = jj >> 2;
                const int T = 2048 >> l;
                float pos = ref + off[jj] / (float)T;
                pos = fminf(fmaxf(pos, 0.f), 1.f);
                off[jj] = pos * (float)(T - 1);
            }
        }
        __syncthreads();

        // Coalesced writeout: 32 x 192 f32 = 1536 float4, 6 per thread.
#pragma unroll
        for (int i = 0; i < 6; ++i) {
            const int idx = t + i * 256;
            const int q = idx / 48, c4 = idx % 48;
            const float4 o = *reinterpret_cast<const float4*>(&Epi[q][c4 * 4]);
            *reinterpret_cast<float4*>(&rows[(size_t)(qrow0 + q) * 192 + c4 * 4]) = o;
        }
    }
}

// ---------------------------------------------------------------------------
// K3: gather + lerp + weighted sum, 4x vectorized.
// One wave per query (8 heads x 8 channel-quads), 4 queries per block.
// ushort4 (8B) gathers; grid 4096 with bid&7 = batch -> XCD L2 affinity.
// ---------------------------------------------------------------------------
__global__ __launch_bounds__(256) void sample_kernel(
    const float* __restrict__ rows,            // [16384,192]  sidx | aw
    const unsigned short* __restrict__ vproj,  // [28672,128]  bf16, level-major
    unsigned short* __restrict__ out_mid)      // [16384,256]  bf16
{
    const int bid = blockIdx.x;                // 0..4095
    const int b = bid & 7;
    const int q0 = (b << 11) + ((bid >> 3) << 2);   // 4 queries/block
    const int t = threadIdx.x;
    const int w = t >> 6, lane = t & 63;
    const int h = lane >> 3, c4 = lane & 7;    // channel = c4*4 .. +3

    __shared__ float srow[4][192];
    {
        const float* src = rows + (size_t)q0 * 192;
#pragma unroll
        for (int i = 0; i < 3; ++i) {
            const int idx = t + i * 256;       // 0..767, coalesced
            srow[idx / 192][idx % 192] = src[idx];
        }
    }
    __syncthreads();

    float acc0 = 0.f, acc1 = 0.f, acc2 = 0.f, acc3 = 0.f;
#pragma unroll
    for (int l = 0; l < 3; ++l) {
        const int T = 2048 >> l;
        const int loff = (l == 0) ? 0 : ((l == 1) ? 16384 : 24576);
#pragma unroll
        for (int p = 0; p < 4; ++p) {
            const int j = h * 12 + l * 4 + p;
            const float wgt  = srow[w][96 + j];
            const float sidx = srow[w][j];
            int ifl = (int)sidx;
            ifl = min(max(ifl, 0), T - 2);
            const float wce = sidx - (float)ifl;
            const size_t base = ((size_t)(loff + b * T + ifl)) * 128 + p * 32 + c4 * 4;
            const ushort4 vf = *reinterpret_cast<const ushort4*>(&vproj[base]);
            const ushort4 vc = *reinterpret_cast<const ushort4*>(&vproj[base + 128]);
            const float f0 = bf2f(vf.x), f1 = bf2f(vf.y), f2 = bf2f(vf.z), f3 = bf2f(vf.w);
            const float g0 = bf2f(vc.x), g1 = bf2f(vc.y), g2 = bf2f(vc.z), g3 = bf2f(vc.w);
            acc0 += wgt * (f0 + wce * (g0 - f0));
            acc1 += wgt * (f1 + wce * (g1 - f1));
            acc2 += wgt * (f2 + wce * (g2 - f2));
            acc3 += wgt * (f3 + wce * (g3 - f3));
        }
    }
    ushort4 o;
    o.x = f2bf(acc0); o.y = f2bf(acc1); o.z = f2bf(acc2); o.w = f2bf(acc3);
    *reinterpret_cast<ushort4*>(&out_mid[(size_t)(q0 + w) * 256 + h * 32 + c4 * 4]) = o;
}

// ---------------------------------------------------------------------------
// K4: output projection, 64x128 tiles -> 512 blocks (2/CU) for latency hiding.
// b = bid&7, row-tile = (bid>>3)&31, col-tile = bid>>8.
// ---------------------------------------------------------------------------
__global__ __launch_bounds__(256) void outproj_kernel(
    const unsigned short* __restrict__ omid,   // [16384,256] bf16
    const float* __restrict__ Wo,              // [256][256] f32
    const float* __restrict__ bo,
    float* __restrict__ out)
{
    __shared__ __align__(16) char SMEM[16896];   // union: staging 12K | epi 16.9K
    auto Asub = reinterpret_cast<unsigned short(*)[64][8]>(SMEM);           // 4 KB
    auto Bsub = reinterpret_cast<unsigned short(*)[128][8]>(SMEM + 4096);   // 8 KB

    const int t = threadIdx.x;
    const int bid = blockIdx.x;
    const int b = bid & 7;
    const int row0 = b * 2048 + ((bid >> 3) & 31) * 64;
    const int col0 = (bid >> 8) * 128;

    const int ar = t >> 2, as = t & 3;           // A staging: row 0..63, slot
    const int w = t >> 6, lane = t & 63;
    const int wr = w >> 1, wc = w & 1;           // wave: 32 rows x 64 cols
    const int fr = lane & 15, sl = lane >> 4;

    f32x4 acc[2][4];
#pragma unroll
    for (int m = 0; m < 2; ++m)
#pragma unroll
        for (int n = 0; n < 4; ++n) acc[m][n] = (f32x4){0.f, 0.f, 0.f, 0.f};

    for (int k0t = 0; k0t < 8; ++k0t) {
        const int k0 = k0t * 32;
        {   // stage A: 16B copies (bf16 src), 1 chunk/thread
            *reinterpret_cast<u16x8*>(&Asub[as][ar][0]) =
                *reinterpret_cast<const u16x8*>(&omid[(size_t)(row0 + ar) * 256 + k0 + as * 8]);
        }
        {   // stage B from raw Wo, 2 chunks/thread
#pragma unroll
            for (int i = 0; i < 2; ++i) {
                const int ch = t + i * 256;
                const int slot = ch >> 7, col = col0 + (ch & 127);
                u16x8 pk;
#pragma unroll
                for (int jj = 0; jj < 8; ++jj)
                    pk[jj] = f2bf(Wo[(size_t)(k0 + slot * 8 + jj) * 256 + col]);
                *reinterpret_cast<u16x8*>(&Bsub[slot][ch & 127][0]) = pk;
            }
        }
        __syncthreads();

        bf16x8 bfrag[4];
#pragma unroll
        for (int n = 0; n < 4; ++n)
            bfrag[n] = *reinterpret_cast<bf16x8*>(&Bsub[sl][wc * 64 + n * 16 + fr][0]);
#pragma unroll
        for (int m = 0; m < 2; ++m) {
            bf16x8 afrag = *reinterpret_cast<bf16x8*>(&Asub[sl][wr * 32 + m * 16 + fr][0]);
#pragma unroll
            for (int n = 0; n < 4; ++n)
                acc[m][n] = __builtin_amdgcn_mfma_f32_16x16x32_bf16(afrag, bfrag[n], acc[m][n], 0, 0, 0);
        }
        __syncthreads();
    }

    float bs[4];
#pragma unroll
    for (int n = 0; n < 4; ++n) bs[n] = bo[col0 + wc * 64 + n * 16 + fr];

    auto Epi2 = reinterpret_cast<float(*)[132]>(SMEM);   // [32][132], aliases staging
#pragma unroll
    for (int m = 0; m < 2; ++m) {
#pragma unroll
        for (int n = 0; n < 4; ++n)
#pragma unroll
            for (int j = 0; j < 4; ++j)
                Epi2[wr * 16 + sl * 4 + j][wc * 64 + n * 16 + fr] = acc[m][n][j] + bs[n];
        __syncthreads();
#pragma unroll
        for (int i = 0; i < 4; ++i) {            // 32x128 f32 = 1024 float4
            const int idx = t + i * 256;
            const int rb = idx >> 5, c4 = idx & 31;
            const int grow = row0 + m * 16 + (rb >> 4) * 32 + (rb & 15);
            const float4 o = *reinterpret_cast<const float4*>(&Epi2[rb][c4 * 4]);
            *reinterpret_cast<float4*>(&out[(size_t)grow * 256 + col0 + c4 * 4]) = o;
        }
        __syncthreads();
    }
}

extern "C" void kernel_launch(void* const* d_in, const int* in_sizes, int n_in,
                              void* d_out, int out_size, void* d_ws, size_t ws_size,
                              hipStream_t stream) {
    (void)in_sizes; (void)n_in; (void)out_size; (void)ws_size;
    const float* query = (const float*)d_in[0];
    const float* refp  = (const float*)d_in[1];
    const float* v0    = (const float*)d_in[2];
    const float* v1    = (const float*)d_in[3];
    const float* v2    = (const float*)d_in[4];
    const float* Woff  = (const float*)d_in[5];
    const float* boff  = (const float*)d_in[6];
    const float* Waw   = (const float*)d_in[7];
    const float* baw   = (const float*)d_in[8];
    const float* Wv    = (const float*)d_in[9];
    const float* bv    = (const float*)d_in[10];
    const float* Wo    = (const float*)d_in[11];
    const float* bo    = (const float*)d_in[12];
    float* out = (float*)d_out;

    char* ws = (char*)d_ws;
    unsigned short* vproj = (unsigned short*)(ws);             // 7,340,032 B
    float*          rows  = (float*)(ws + 7340032);            // 12,582,912 B
    unsigned short* omid  = (unsigned short*)(ws + 19922944);  // 8,388,608 B

    // K12: merged vproj (448 blocks, 64x128) + logits (512 blocks, 32x192)
    fused_k12_kernel<<<960, 256, 0, stream>>>(v0, v1, v2, Wv, bv, vproj,
                                              query, Woff, Waw, boff, baw,
                                              refp, rows);

    // K3: gather + lerp + weighted sum (vectorized, XCD-aligned)
    sample_kernel<<<4096, 256, 0, stream>>>(rows, vproj, omid);

    // K4: output projection (64x128 tiles, 512 blocks)
    outproj_kernel<<<512, 256, 0, stream>>>(omid, Wo, bo, out);
}